// Round 2
// baseline (272.048 us; speedup 1.0000x reference)
//
#include <hip/hip_runtime.h>
#include <hip/hip_bf16.h>

typedef __attribute__((ext_vector_type(8))) short bf16x8;
typedef __attribute__((ext_vector_type(4))) short s16x4;
typedef __attribute__((ext_vector_type(2))) int i32x2;
typedef __attribute__((ext_vector_type(4))) float f32x4;

__device__ __forceinline__ short f2bf(float f) {
  unsigned u = __builtin_bit_cast(unsigned, f);
  u = (u + 0x7FFFu + ((u >> 16) & 1u)) >> 16;
  return (short)u;
}

__device__ __forceinline__ void gload_lds16(const void* g, void* l) {
  __builtin_amdgcn_global_load_lds(
      (const __attribute__((address_space(1))) void*)g,
      (__attribute__((address_space(3))) void*)l, 16, 0, 0);
}

__device__ __forceinline__ f32x4 mfma16(s16x4 a, s16x4 b, f32x4 c) {
#if __has_builtin(__builtin_amdgcn_mfma_f32_16x16x16bf16_1k)
  return __builtin_amdgcn_mfma_f32_16x16x16bf16_1k(a, b, c, 0, 0, 0);
#else
  asm("v_mfma_f32_16x16x16_bf16 %0, %1, %2, %0" : "+v"(c) : "v"(a), "v"(b));
  return c;
#endif
}

// ---------------------------------------------------------------- prep kernels

// x (B,240,512) fp32 -> xb (B*256,512) bf16, zero-padded rows 240..255
__global__ void k_convert_x(const float* __restrict__ x, short* __restrict__ xb) {
  int i = blockIdx.x * 256 + threadIdx.x;      // group of 4 elements
  int c4 = i & 127;
  int row = i >> 7;                            // 0..32767
  int b = row >> 8, t = row & 255;
  s16x4 o = {0, 0, 0, 0};
  if (t < 240) {
    const float4 v = *(const float4*)(x + (size_t)(b * 240 + t) * 512 + c4 * 4);
    o.x = f2bf(v.x); o.y = f2bf(v.y); o.z = f2bf(v.z); o.w = f2bf(v.w);
  }
  *(s16x4*)(xb + (size_t)row * 512 + c4 * 4) = o;
}

// W (K,N) fp32 -> Wt (N,K) bf16
__global__ void k_transpose_w(const float* __restrict__ W, short* __restrict__ Wt,
                              int K, int N) {
  int i = blockIdx.x * 256 + threadIdx.x;      // n*K + k
  if (i >= K * N) return;
  int k = i % K, n = i / K;
  Wt[i] = f2bf(W[(size_t)k * N + n]);
}

// rel_bias_table (961,16) -> expB in swapped-QK fragment layout:
// expB[((h*16+qtl)*15 + j)*64 + lane][r] = exp(bias(h, q=qtl*16+(lane&15),
//                                                   k=j*16+4*(lane>>4)+r))
__global__ void k_biasfrag(const float* __restrict__ table, float* __restrict__ expB) {
  int i = blockIdx.x * 256 + threadIdx.x;      // 245760 threads
  int lane = i & 63;
  int rest = i >> 6;
  int j = rest % 15;
  int hq = rest / 15;                          // h*16 + qtl
  int q = (hq & 15) * 16 + (lane & 15);
  int h = hq >> 4;
  int kbase = j * 16 + ((lane >> 4) << 2);
  float4 o;
  float* op = &o.x;
#pragma unroll
  for (int r = 0; r < 4; ++r) {
    int k = kbase + r;
    int idx = ((q >> 4) - (k >> 4) + 15) * 31 + ((q & 15) - (k & 15) + 15);
    op[r] = __builtin_amdgcn_exp2f(table[idx * 16 + h] * 1.4426950408889634f);
  }
  *(float4*)(expB + (size_t)i * 4) = o;
}

// ---------------------------------------------------------------- GEMM
// C = A(M x 512) * Bt(N x 512)^T + bias ; 128x128 tile, 4 waves, BK=32
template <int MODE>
__global__ __launch_bounds__(256, 2)
void k_gemm(const short* __restrict__ A, const short* __restrict__ Bt,
            const float* __restrict__ bias,
            short* __restrict__ qo, short* __restrict__ ko, short* __restrict__ vo,
            float* __restrict__ fo) {
  __shared__ alignas(16) short lds[2][8][512];   // frag-ordered: [blk][lane*8]
  const int lane = threadIdx.x & 63;
  const int w = threadIdx.x >> 6;
  const int n0 = blockIdx.x * 128;
  const int m0 = blockIdx.y * 128;
  const int wr = w >> 1, wc = w & 1;
  const int arow = lane & 15;
  const int kc8 = (lane >> 4) * 8;

  f32x4 acc[4][4] = {};

  for (int kt = 0; kt < 16; ++kt) {
    const int k0 = kt * 32;
#pragma unroll
    for (int s = 0; s < 2; ++s) {
      const int blk = 2 * w + s;
      gload_lds16(A + (size_t)(m0 + blk * 16 + arow) * 512 + k0 + kc8, &lds[0][blk][0]);
      gload_lds16(Bt + (size_t)(n0 + blk * 16 + arow) * 512 + k0 + kc8, &lds[1][blk][0]);
    }
    __syncthreads();
    bf16x8 af[4], bfr[4];
#pragma unroll
    for (int i = 0; i < 4; ++i) af[i] = *(const bf16x8*)&lds[0][wr * 4 + i][lane * 8];
#pragma unroll
    for (int j = 0; j < 4; ++j) bfr[j] = *(const bf16x8*)&lds[1][wc * 4 + j][lane * 8];
#pragma unroll
    for (int i = 0; i < 4; ++i)
#pragma unroll
      for (int j = 0; j < 4; ++j)
        acc[i][j] = __builtin_amdgcn_mfma_f32_16x16x32_bf16(af[i], bfr[j], acc[i][j], 0, 0, 0);
    __syncthreads();
  }

  // Q pre-scaled by head_dim^-0.5 * log2(e) so softmax runs in exp2 domain
  const float sc = 0.17677669529663687f * 1.4426950408889634f;
#pragma unroll
  for (int i = 0; i < 4; ++i) {
    const int mbase = m0 + (wr * 4 + i) * 16 + ((lane >> 4) << 2);
#pragma unroll
    for (int j = 0; j < 4; ++j) {
      const int c = n0 + (wc * 4 + j) * 16 + arow;
      const float bv = bias[c];
#pragma unroll
      for (int r = 0; r < 4; ++r) {
        float val = acc[i][j][r] + bv;
        const int mm = mbase + r;
        const int bb = mm >> 8, tt = mm & 255;
        if (MODE == 0) {
          const int part = c >> 9;
          const int hh = (c >> 5) & 15;
          const int dd = c & 31;
          const size_t off = ((size_t)(bb * 16 + hh) * 256 + tt) * 32 + dd;
          if (part == 0)       qo[off] = f2bf(val * sc);
          else if (part == 1)  ko[off] = f2bf(val);
          else                 vo[off] = f2bf(val);
        } else {
          if (tt < 240) fo[(size_t)(bb * 240 + tt) * 512 + c] = val;
        }
      }
    }
  }
}

// ---------------------------------------------------------------- attention
// One WG (4 waves) per (b,h). Swapped QK^T: lane holds S[q=lane&15][k=j*16+4g+r]
// -> softmax row fully lane-local (2 shfl per reduce); P packs directly into
// the A-fragment of mfma_f32_16x16x16_bf16 for PV (no LDS transpose).
__global__ __launch_bounds__(256, 4)
void k_attn(const short* __restrict__ Qg, const short* __restrict__ Kg,
            const short* __restrict__ Vg, const float* __restrict__ expB,
            short* __restrict__ O) {
  __shared__ alignas(16) short ldsK[15 * 512];      // frag-ordered K tiles
  __shared__ alignas(16) short ldsVT[32 * 260];     // V^T [d][t], stride 260
  const int lane = threadIdx.x & 63;
  const int w = threadIdx.x >> 6;
  const int bh = blockIdx.x;
  const int h = bh & 15, b = bh >> 4;
  const short* Qb = Qg + (size_t)bh * 8192;
  const short* Kb = Kg + (size_t)bh * 8192;
  const short* Vb = Vg + (size_t)bh * 8192;
  const int arow = lane & 15;
  const int g = lane >> 4;

#pragma unroll
  for (int kt = 0; kt < 15; ++kt)
    if ((kt & 3) == w)
      gload_lds16(Kb + (kt * 16 + arow) * 32 + g * 8, &ldsK[kt * 512]);

  // build V^T in LDS (coalesced global reads, conflict-free scalar writes)
#pragma unroll
  for (int p = 0; p < 4; ++p) {
    int gi = p * 256 + threadIdx.x;
    int t = gi >> 2, dg = (gi & 3) * 8;
    bf16x8 v = *(const bf16x8*)(Vb + t * 32 + dg);
#pragma unroll
    for (int e = 0; e < 8; ++e)
      ldsVT[(dg + e) * 260 + t] = v[e];
  }

  bf16x8 qf[4];
#pragma unroll
  for (int i = 0; i < 4; ++i)
    qf[i] = *(const bf16x8*)(Qb + ((w * 4 + i) * 16 + arow) * 32 + g * 8);
  __syncthreads();

  const f32x4 zf = {0.f, 0.f, 0.f, 0.f};
#pragma unroll
  for (int qt = 0; qt < 4; ++qt) {
    // ---- QK^T (swapped operands) ----
    f32x4 sacc[15];
#pragma unroll
    for (int j = 0; j < 15; ++j) {
      bf16x8 kf = *(const bf16x8*)&ldsK[j * 512 + lane * 8];
      sacc[j] = __builtin_amdgcn_mfma_f32_16x16x32_bf16(kf, qf[qt], zf, 0, 0, 0);
    }
    // ---- row max (row is lane-local, then 2-shfl butterfly across groups) ----
    float m = fmaxf(fmaxf(sacc[0][0], sacc[0][1]), fmaxf(sacc[0][2], sacc[0][3]));
#pragma unroll
    for (int j = 1; j < 15; ++j)
      m = fmaxf(m, fmaxf(fmaxf(sacc[j][0], sacc[j][1]), fmaxf(sacc[j][2], sacc[j][3])));
    m = fmaxf(m, __shfl_xor(m, 16));
    m = fmaxf(m, __shfl_xor(m, 32));
    // ---- p = exp2(S - m) * exp(bias), pack to bf16 A-frags ----
    const float* ebp = expB + (size_t)((h * 16 + w * 4 + qt) * 15) * 256 + lane * 4;
    float sum = 0.f;
    s16x4 pa[15];
#pragma unroll
    for (int j = 0; j < 15; ++j) {
      float4 eb = *(const float4*)(ebp + j * 256);
      float p0 = __builtin_amdgcn_exp2f(sacc[j][0] - m) * eb.x;
      float p1 = __builtin_amdgcn_exp2f(sacc[j][1] - m) * eb.y;
      float p2 = __builtin_amdgcn_exp2f(sacc[j][2] - m) * eb.z;
      float p3 = __builtin_amdgcn_exp2f(sacc[j][3] - m) * eb.w;
      sum += (p0 + p1) + (p2 + p3);
      i32x2 pk;
      asm("v_cvt_pk_bf16_f32 %0, %1, %2" : "=v"(pk.x) : "v"(p0), "v"(p1));
      asm("v_cvt_pk_bf16_f32 %0, %1, %2" : "=v"(pk.y) : "v"(p2), "v"(p3));
      pa[j] = __builtin_bit_cast(s16x4, pk);
    }
    sum += __shfl_xor(sum, 16);
    sum += __shfl_xor(sum, 32);
    float rs = __builtin_amdgcn_rcpf(sum);
    // redistribute 1/sum from row-holder lanes (arow=q) to out-row lanes (4g+r)
    float rsr[4];
#pragma unroll
    for (int r = 0; r < 4; ++r)
      rsr[r] = __shfl(rs, (lane & 48) + ((lane & 48) >> 2) + r, 64);
    // ---- PV: P A-frags x V^T B-frags, K=16 ----
    f32x4 oacc[2] = {};
#pragma unroll
    for (int j = 0; j < 15; ++j) {
#pragma unroll
      for (int dt = 0; dt < 2; ++dt) {
        s16x4 vt = *(const s16x4*)&ldsVT[(dt * 16 + arow) * 260 + j * 16 + g * 4];
        oacc[dt] = mfma16(pa[j], vt, oacc[dt]);
      }
    }
    const int q0 = (w * 4 + qt) * 16;
#pragma unroll
    for (int dt = 0; dt < 2; ++dt)
#pragma unroll
      for (int r = 0; r < 4; ++r)
        O[(size_t)(b * 256 + q0 + 4 * g + r) * 512 + h * 32 + dt * 16 + arow] =
            f2bf(oacc[dt][r] * rsr[r]);
  }
}

// ---------------------------------------------------------------- launch

extern "C" void kernel_launch(void* const* d_in, const int* in_sizes, int n_in,
                              void* d_out, int out_size, void* d_ws, size_t ws_size,
                              hipStream_t stream) {
  const float* x      = (const float*)d_in[0];
  const float* qkv_w  = (const float*)d_in[1];
  const float* qkv_b  = (const float*)d_in[2];
  const float* proj_w = (const float*)d_in[3];
  const float* proj_b = (const float*)d_in[4];
  const float* table  = (const float*)d_in[5];
  float* out = (float*)d_out;

  char* ws = (char*)d_ws;
  short* xb      = (short*)(ws);                 // 33,554,432 B (reused as attn_out)
  short* Qg      = (short*)(ws + 33554432u);     // 33,554,432 B
  short* Kg      = (short*)(ws + 67108864u);     // 33,554,432 B
  short* Vg      = (short*)(ws + 100663296u);    // 33,554,432 B
  float* expBf   = (float*)(ws + 134217728u);    //  3,932,160 B
  short* qkv_wt  = (short*)(ws + 138412032u);    //  1,572,864 B
  short* proj_wt = (short*)(ws + 139984896u);    //    524,288 B

  k_convert_x<<<16384, 256, 0, stream>>>(x, xb);
  k_transpose_w<<<(1536 * 512) / 256, 256, 0, stream>>>(qkv_w, qkv_wt, 512, 1536);
  k_transpose_w<<<(512 * 512) / 256, 256, 0, stream>>>(proj_w, proj_wt, 512, 512);
  k_biasfrag<<<960, 256, 0, stream>>>(table, expBf);
  k_gemm<0><<<dim3(12, 256), 256, 0, stream>>>(xb, qkv_wt, qkv_b, Qg, Kg, Vg, nullptr);
  k_attn<<<2048, 256, 0, stream>>>(Qg, Kg, Vg, expBf, xb);
  k_gemm<1><<<dim3(4, 256), 256, 0, stream>>>(xb, proj_wt, proj_b, nullptr, nullptr, nullptr, out);
}

// Round 3
// 261.552 us; speedup vs baseline: 1.0401x; 1.0401x over previous
//
#include <hip/hip_runtime.h>
#include <hip/hip_bf16.h>

typedef __attribute__((ext_vector_type(8))) short bf16x8;
typedef __attribute__((ext_vector_type(4))) short s16x4;
typedef __attribute__((ext_vector_type(2))) int i32x2;
typedef __attribute__((ext_vector_type(4))) float f32x4;

__device__ __forceinline__ short f2bf(float f) {
  unsigned u = __builtin_bit_cast(unsigned, f);
  u = (u + 0x7FFFu + ((u >> 16) & 1u)) >> 16;
  return (short)u;
}

__device__ __forceinline__ void gload_lds16(const void* g, void* l) {
  __builtin_amdgcn_global_load_lds(
      (const __attribute__((address_space(1))) void*)g,
      (__attribute__((address_space(3))) void*)l, 16, 0, 0);
}

__device__ __forceinline__ f32x4 mfma16(s16x4 a, s16x4 b, f32x4 c) {
#if __has_builtin(__builtin_amdgcn_mfma_f32_16x16x16bf16_1k)
  return __builtin_amdgcn_mfma_f32_16x16x16bf16_1k(a, b, c, 0, 0, 0);
#else
  asm("v_mfma_f32_16x16x16_bf16 %0, %1, %2, %0" : "+v"(c) : "v"(a), "v"(b));
  return c;
#endif
}

// ---------------------------------------------------------------- prep kernels

// x (B,240,512) fp32 -> xb (B*256,512) bf16, zero-padded rows 240..255
__global__ void k_convert_x(const float* __restrict__ x, short* __restrict__ xb) {
  int i = blockIdx.x * 256 + threadIdx.x;      // group of 4 elements
  int c4 = i & 127;
  int row = i >> 7;                            // 0..32767
  int b = row >> 8, t = row & 255;
  s16x4 o = {0, 0, 0, 0};
  if (t < 240) {
    const float4 v = *(const float4*)(x + (size_t)(b * 240 + t) * 512 + c4 * 4);
    o.x = f2bf(v.x); o.y = f2bf(v.y); o.z = f2bf(v.z); o.w = f2bf(v.w);
  }
  *(s16x4*)(xb + (size_t)row * 512 + c4 * 4) = o;
}

// W (K,N) fp32 -> Wt (N,K) bf16
__global__ void k_transpose_w(const float* __restrict__ W, short* __restrict__ Wt,
                              int K, int N) {
  int i = blockIdx.x * 256 + threadIdx.x;      // n*K + k
  if (i >= K * N) return;
  int k = i % K, n = i / K;
  Wt[i] = f2bf(W[(size_t)k * N + n]);
}

// rel_bias_table (961,16) -> expB in swapped-QK fragment layout:
// expB[((h*16+qtl)*15 + j)*64 + lane][r] = exp(bias(h, q=qtl*16+(lane&15),
//                                                   k=j*16+4*(lane>>4)+r))
__global__ void k_biasfrag(const float* __restrict__ table, float* __restrict__ expB) {
  int i = blockIdx.x * 256 + threadIdx.x;      // 245760 threads
  int lane = i & 63;
  int rest = i >> 6;
  int j = rest % 15;
  int hq = rest / 15;                          // h*16 + qtl
  int q = (hq & 15) * 16 + (lane & 15);
  int h = hq >> 4;
  int kbase = j * 16 + ((lane >> 4) << 2);
  float4 o;
  float* op = &o.x;
#pragma unroll
  for (int r = 0; r < 4; ++r) {
    int k = kbase + r;
    int idx = ((q >> 4) - (k >> 4) + 15) * 31 + ((q & 15) - (k & 15) + 15);
    op[r] = __builtin_amdgcn_exp2f(table[idx * 16 + h] * 1.4426950408889634f);
  }
  *(float4*)(expB + (size_t)i * 4) = o;
}

// ---------------------------------------------------------------- GEMM
// C = A(M x 512) * Bt(N x 512)^T + bias ; 128x128 tile, 4 waves, BK=32,
// double-buffered LDS (stage t+1 before computing t -> load latency hidden
// under 16 MFMA + 8 ds_read; single barrier per K-step), XCD-swizzled grid.
template <int MODE, int NT>
__global__ __launch_bounds__(256, 4)
void k_gemm(const short* __restrict__ A, const short* __restrict__ Bt,
            const float* __restrict__ bias,
            short* __restrict__ qo, short* __restrict__ ko, short* __restrict__ vo,
            float* __restrict__ fo) {
  __shared__ alignas(16) short lds[2][2][8][512];   // [buf][A/B][blk16][frag]
  const int lane = threadIdx.x & 63;
  const int w = threadIdx.x >> 6;
  // bijective XCD swizzle (grid = NT*256, divisible by 8)
  const int nwg = NT * 256;
  const int bid = blockIdx.x;
  const int swz = (bid & 7) * (nwg >> 3) + (bid >> 3);
  const int n0 = (swz % NT) * 128;
  const int m0 = (swz / NT) * 128;
  const int wr = w >> 1, wc = w & 1;
  const int arow = lane & 15;
  const int kc8 = (lane >> 4) * 8;

  const short* Ap = A + (size_t)(m0 + 2 * w * 16 + arow) * 512 + kc8;
  const short* Bp = Bt + (size_t)(n0 + 2 * w * 16 + arow) * 512 + kc8;

#define STAGE(buf, k0)                                              \
  {                                                                 \
    gload_lds16(Ap + (k0), &lds[buf][0][2 * w][0]);                 \
    gload_lds16(Ap + 512 * 16 + (k0), &lds[buf][0][2 * w + 1][0]);  \
    gload_lds16(Bp + (k0), &lds[buf][1][2 * w][0]);                 \
    gload_lds16(Bp + 512 * 16 + (k0), &lds[buf][1][2 * w + 1][0]);  \
  }

  f32x4 acc[4][4] = {};
  STAGE(0, 0);
  __syncthreads();
  int cur = 0;
#pragma unroll
  for (int kt = 0; kt < 16; ++kt) {
    if (kt < 15) STAGE(cur ^ 1, (kt + 1) * 32);
    bf16x8 af[4], bfr[4];
#pragma unroll
    for (int i = 0; i < 4; ++i) af[i] = *(const bf16x8*)&lds[cur][0][wr * 4 + i][lane * 8];
#pragma unroll
    for (int j = 0; j < 4; ++j) bfr[j] = *(const bf16x8*)&lds[cur][1][wc * 4 + j][lane * 8];
#pragma unroll
    for (int i = 0; i < 4; ++i)
#pragma unroll
      for (int j = 0; j < 4; ++j)
        acc[i][j] = __builtin_amdgcn_mfma_f32_16x16x32_bf16(af[i], bfr[j], acc[i][j], 0, 0, 0);
    __syncthreads();   // drains vmcnt(0) AFTER this step's compute
    cur ^= 1;
  }
#undef STAGE

  // Q pre-scaled by head_dim^-0.5 * log2(e) so softmax runs in exp2 domain
  const float sc = 0.17677669529663687f * 1.4426950408889634f;
#pragma unroll
  for (int i = 0; i < 4; ++i) {
    const int mbase = m0 + (wr * 4 + i) * 16 + ((lane >> 4) << 2);
#pragma unroll
    for (int j = 0; j < 4; ++j) {
      const int c = n0 + (wc * 4 + j) * 16 + arow;
      const float bv = bias[c];
#pragma unroll
      for (int r = 0; r < 4; ++r) {
        float val = acc[i][j][r] + bv;
        const int mm = mbase + r;
        const int bb = mm >> 8, tt = mm & 255;
        if (MODE == 0) {
          const int part = c >> 9;
          const int hh = (c >> 5) & 15;
          const int dd = c & 31;
          const size_t off = ((size_t)(bb * 16 + hh) * 256 + tt) * 32 + dd;
          if (part == 0)       qo[off] = f2bf(val * sc);
          else if (part == 1)  ko[off] = f2bf(val);
          else                 vo[off] = f2bf(val);
        } else {
          if (tt < 240) fo[(size_t)(bb * 240 + tt) * 512 + c] = val;
        }
      }
    }
  }
}

// ---------------------------------------------------------------- attention
// One WG (4 waves) per (b,h). Swapped QK^T: lane holds S[q=lane&15][k=j*16+4g+r]
// -> softmax row fully lane-local (2 shfl per reduce); P packs directly into
// the A-fragment of mfma_f32_16x16x16_bf16 for PV (no LDS transpose).
__global__ __launch_bounds__(256, 4)
void k_attn(const short* __restrict__ Qg, const short* __restrict__ Kg,
            const short* __restrict__ Vg, const float* __restrict__ expB,
            short* __restrict__ O) {
  __shared__ alignas(16) short ldsK[15 * 512];      // frag-ordered K tiles
  __shared__ alignas(16) short ldsVT[32 * 260];     // V^T [d][t], stride 260
  const int lane = threadIdx.x & 63;
  const int w = threadIdx.x >> 6;
  const int bh = blockIdx.x;
  const int h = bh & 15, b = bh >> 4;
  const short* Qb = Qg + (size_t)bh * 8192;
  const short* Kb = Kg + (size_t)bh * 8192;
  const short* Vb = Vg + (size_t)bh * 8192;
  const int arow = lane & 15;
  const int g = lane >> 4;

#pragma unroll
  for (int kt = 0; kt < 15; ++kt)
    if ((kt & 3) == w)
      gload_lds16(Kb + (kt * 16 + arow) * 32 + g * 8, &ldsK[kt * 512]);

  // build V^T in LDS (coalesced global reads, conflict-free scalar writes)
#pragma unroll
  for (int p = 0; p < 4; ++p) {
    int gi = p * 256 + threadIdx.x;
    int t = gi >> 2, dg = (gi & 3) * 8;
    bf16x8 v = *(const bf16x8*)(Vb + t * 32 + dg);
#pragma unroll
    for (int e = 0; e < 8; ++e)
      ldsVT[(dg + e) * 260 + t] = v[e];
  }

  bf16x8 qf[4];
#pragma unroll
  for (int i = 0; i < 4; ++i)
    qf[i] = *(const bf16x8*)(Qb + ((w * 4 + i) * 16 + arow) * 32 + g * 8);
  __syncthreads();

  const f32x4 zf = {0.f, 0.f, 0.f, 0.f};
#pragma unroll
  for (int qt = 0; qt < 4; ++qt) {
    // ---- QK^T (swapped operands) ----
    f32x4 sacc[15];
#pragma unroll
    for (int j = 0; j < 15; ++j) {
      bf16x8 kf = *(const bf16x8*)&ldsK[j * 512 + lane * 8];
      sacc[j] = __builtin_amdgcn_mfma_f32_16x16x32_bf16(kf, qf[qt], zf, 0, 0, 0);
    }
    // ---- row max (row is lane-local, then 2-shfl butterfly across groups) ----
    float m = fmaxf(fmaxf(sacc[0][0], sacc[0][1]), fmaxf(sacc[0][2], sacc[0][3]));
#pragma unroll
    for (int j = 1; j < 15; ++j)
      m = fmaxf(m, fmaxf(fmaxf(sacc[j][0], sacc[j][1]), fmaxf(sacc[j][2], sacc[j][3])));
    m = fmaxf(m, __shfl_xor(m, 16));
    m = fmaxf(m, __shfl_xor(m, 32));
    // ---- p = exp2(S - m) * exp(bias), pack to bf16 A-frags ----
    const float* ebp = expB + (size_t)((h * 16 + w * 4 + qt) * 15) * 256 + lane * 4;
    float sum = 0.f;
    s16x4 pa[15];
#pragma unroll
    for (int j = 0; j < 15; ++j) {
      float4 eb = *(const float4*)(ebp + j * 256);
      float p0 = __builtin_amdgcn_exp2f(sacc[j][0] - m) * eb.x;
      float p1 = __builtin_amdgcn_exp2f(sacc[j][1] - m) * eb.y;
      float p2 = __builtin_amdgcn_exp2f(sacc[j][2] - m) * eb.z;
      float p3 = __builtin_amdgcn_exp2f(sacc[j][3] - m) * eb.w;
      sum += (p0 + p1) + (p2 + p3);
      i32x2 pk;
      asm("v_cvt_pk_bf16_f32 %0, %1, %2" : "=v"(pk.x) : "v"(p0), "v"(p1));
      asm("v_cvt_pk_bf16_f32 %0, %1, %2" : "=v"(pk.y) : "v"(p2), "v"(p3));
      pa[j] = __builtin_bit_cast(s16x4, pk);
    }
    sum += __shfl_xor(sum, 16);
    sum += __shfl_xor(sum, 32);
    float rs = __builtin_amdgcn_rcpf(sum);
    // redistribute 1/sum from row-holder lanes (arow=q) to out-row lanes (4g+r)
    float rsr[4];
#pragma unroll
    for (int r = 0; r < 4; ++r)
      rsr[r] = __shfl(rs, (lane & 48) + ((lane & 48) >> 2) + r, 64);
    // ---- PV: P A-frags x V^T B-frags, K=16 ----
    f32x4 oacc[2] = {};
#pragma unroll
    for (int j = 0; j < 15; ++j) {
#pragma unroll
      for (int dt = 0; dt < 2; ++dt) {
        s16x4 vt = *(const s16x4*)&ldsVT[(dt * 16 + arow) * 260 + j * 16 + g * 4];
        oacc[dt] = mfma16(pa[j], vt, oacc[dt]);
      }
    }
    const int q0 = (w * 4 + qt) * 16;
#pragma unroll
    for (int dt = 0; dt < 2; ++dt)
#pragma unroll
      for (int r = 0; r < 4; ++r)
        O[(size_t)(b * 256 + q0 + 4 * g + r) * 512 + h * 32 + dt * 16 + arow] =
            f2bf(oacc[dt][r] * rsr[r]);
  }
}

// ---------------------------------------------------------------- launch

extern "C" void kernel_launch(void* const* d_in, const int* in_sizes, int n_in,
                              void* d_out, int out_size, void* d_ws, size_t ws_size,
                              hipStream_t stream) {
  const float* x      = (const float*)d_in[0];
  const float* qkv_w  = (const float*)d_in[1];
  const float* qkv_b  = (const float*)d_in[2];
  const float* proj_w = (const float*)d_in[3];
  const float* proj_b = (const float*)d_in[4];
  const float* table  = (const float*)d_in[5];
  float* out = (float*)d_out;

  char* ws = (char*)d_ws;
  short* xb      = (short*)(ws);                 // 33,554,432 B (reused as attn_out)
  short* Qg      = (short*)(ws + 33554432u);     // 33,554,432 B
  short* Kg      = (short*)(ws + 67108864u);     // 33,554,432 B
  short* Vg      = (short*)(ws + 100663296u);    // 33,554,432 B
  float* expBf   = (float*)(ws + 134217728u);    //  3,932,160 B
  short* qkv_wt  = (short*)(ws + 138412032u);    //  1,572,864 B
  short* proj_wt = (short*)(ws + 139984896u);    //    524,288 B

  k_convert_x<<<16384, 256, 0, stream>>>(x, xb);
  k_transpose_w<<<(1536 * 512) / 256, 256, 0, stream>>>(qkv_w, qkv_wt, 512, 1536);
  k_transpose_w<<<(512 * 512) / 256, 256, 0, stream>>>(proj_w, proj_wt, 512, 512);
  k_biasfrag<<<960, 256, 0, stream>>>(table, expBf);
  k_gemm<0, 12><<<3072, 256, 0, stream>>>(xb, qkv_wt, qkv_b, Qg, Kg, Vg, nullptr);
  k_attn<<<2048, 256, 0, stream>>>(Qg, Kg, Vg, expBf, xb);
  k_gemm<1, 4><<<1024, 256, 0, stream>>>(xb, proj_wt, proj_b, nullptr, nullptr, nullptr, out);
}

// Round 4
// 258.065 us; speedup vs baseline: 1.0542x; 1.0135x over previous
//
#include <hip/hip_runtime.h>
#include <hip/hip_bf16.h>

typedef __attribute__((ext_vector_type(8))) short bf16x8;
typedef __attribute__((ext_vector_type(4))) short s16x4;
typedef __attribute__((ext_vector_type(2))) int i32x2;
typedef __attribute__((ext_vector_type(4))) float f32x4;

__device__ __forceinline__ short f2bf(float f) {
  unsigned u = __builtin_bit_cast(unsigned, f);
  u = (u + 0x7FFFu + ((u >> 16) & 1u)) >> 16;
  return (short)u;
}

__device__ __forceinline__ void gload_lds16(const void* g, void* l) {
  __builtin_amdgcn_global_load_lds(
      (const __attribute__((address_space(1))) void*)g,
      (__attribute__((address_space(3))) void*)l, 16, 0, 0);
}

__device__ __forceinline__ f32x4 mfma16(s16x4 a, s16x4 b, f32x4 c) {
#if __has_builtin(__builtin_amdgcn_mfma_f32_16x16x16bf16_1k)
  return __builtin_amdgcn_mfma_f32_16x16x16bf16_1k(a, b, c, 0, 0, 0);
#else
  asm("v_mfma_f32_16x16x16_bf16 %0, %1, %2, %0" : "+v"(c) : "v"(a), "v"(b));
  return c;
#endif
}

#define SBAR()      asm volatile("s_barrier" ::: "memory")
#define WAIT_VM4()  asm volatile("s_waitcnt vmcnt(4)" ::: "memory")
#define WAIT_VM0()  asm volatile("s_waitcnt vmcnt(0)" ::: "memory")
#define WAIT_LGKM0() asm volatile("s_waitcnt lgkmcnt(0)" ::: "memory")

// ---------------------------------------------------------------- prep kernels

// x (B,240,512) fp32 -> xb (B*256,512) bf16, zero-padded rows 240..255
__global__ void k_convert_x(const float* __restrict__ x, short* __restrict__ xb) {
  int i = blockIdx.x * 256 + threadIdx.x;      // group of 4 elements
  int c4 = i & 127;
  int row = i >> 7;                            // 0..32767
  int b = row >> 8, t = row & 255;
  s16x4 o = {0, 0, 0, 0};
  if (t < 240) {
    const float4 v = *(const float4*)(x + (size_t)(b * 240 + t) * 512 + c4 * 4);
    o.x = f2bf(v.x); o.y = f2bf(v.y); o.z = f2bf(v.z); o.w = f2bf(v.w);
  }
  *(s16x4*)(xb + (size_t)row * 512 + c4 * 4) = o;
}

// W (K,N) fp32 -> Wt (N,K) bf16
__global__ void k_transpose_w(const float* __restrict__ W, short* __restrict__ Wt,
                              int K, int N) {
  int i = blockIdx.x * 256 + threadIdx.x;      // n*K + k
  if (i >= K * N) return;
  int k = i % K, n = i / K;
  Wt[i] = f2bf(W[(size_t)k * N + n]);
}

// rel_bias_table (961,16) -> expB in swapped-QK fragment layout:
// expB[((h*16+qtl)*15 + j)*64 + lane][r] = exp(bias(h, q=qtl*16+(lane&15),
//                                                   k=j*16+4*(lane>>4)+r))
__global__ void k_biasfrag(const float* __restrict__ table, float* __restrict__ expB) {
  int i = blockIdx.x * 256 + threadIdx.x;      // 245760 threads
  int lane = i & 63;
  int rest = i >> 6;
  int j = rest % 15;
  int hq = rest / 15;                          // h*16 + qtl
  int q = (hq & 15) * 16 + (lane & 15);
  int h = hq >> 4;
  int kbase = j * 16 + ((lane >> 4) << 2);
  float4 o;
  float* op = &o.x;
#pragma unroll
  for (int r = 0; r < 4; ++r) {
    int k = kbase + r;
    int idx = ((q >> 4) - (k >> 4) + 15) * 31 + ((q & 15) - (k & 15) + 15);
    op[r] = __builtin_amdgcn_exp2f(table[idx * 16 + h] * 1.4426950408889634f);
  }
  *(float4*)(expB + (size_t)i * 4) = o;
}

// ---------------------------------------------------------------- GEMM
// C = A(M x 512) * Bt(N x 512)^T + bias ; 128x128 tile, 4 waves, BK=32.
// Counted-vmcnt 2-deep pipeline (T3/T4): raw s_barrier (no vmcnt drain),
// vmcnt(4) waits only the oldest stage; prefetch stays in flight across
// barriers. XCD-swizzled 1-D grid.
template <int MODE, int NT>
__global__ __launch_bounds__(256, 4)
void k_gemm(const short* __restrict__ A, const short* __restrict__ Bt,
            const float* __restrict__ bias,
            short* __restrict__ qo, short* __restrict__ ko, short* __restrict__ vo,
            float* __restrict__ fo) {
  __shared__ alignas(16) short lds[2][2][8][512];   // [buf][A/B][blk16][frag]
  const int lane = threadIdx.x & 63;
  const int w = threadIdx.x >> 6;
  // bijective XCD swizzle (grid = NT*256, divisible by 8)
  const int nwg = NT * 256;
  const int bid = blockIdx.x;
  const int swz = (bid & 7) * (nwg >> 3) + (bid >> 3);
  const int n0 = (swz % NT) * 128;
  const int m0 = (swz / NT) * 128;
  const int wr = w >> 1, wc = w & 1;
  const int arow = lane & 15;
  const int kc8 = (lane >> 4) * 8;

  const short* Ap = A + (size_t)(m0 + 2 * w * 16 + arow) * 512 + kc8;
  const short* Bp = Bt + (size_t)(n0 + 2 * w * 16 + arow) * 512 + kc8;

#define STAGE(buf, k0)                                              \
  {                                                                 \
    gload_lds16(Ap + (k0), &lds[buf][0][2 * w][0]);                 \
    gload_lds16(Ap + 512 * 16 + (k0), &lds[buf][0][2 * w + 1][0]);  \
    gload_lds16(Bp + (k0), &lds[buf][1][2 * w][0]);                 \
    gload_lds16(Bp + 512 * 16 + (k0), &lds[buf][1][2 * w + 1][0]);  \
  }

  f32x4 acc[4][4] = {};
  STAGE(0, 0);
  STAGE(1, 32);
#pragma unroll
  for (int kt = 0; kt < 16; ++kt) {
    const int cur = kt & 1;
    if (kt < 14) WAIT_VM4(); else WAIT_VM0();   // oldest stage (tile kt) landed
    SBAR();                                     // ...for every wave
    bf16x8 af[4], bfr[4];
#pragma unroll
    for (int i = 0; i < 4; ++i) af[i] = *(const bf16x8*)&lds[cur][0][wr * 4 + i][lane * 8];
#pragma unroll
    for (int j = 0; j < 4; ++j) bfr[j] = *(const bf16x8*)&lds[cur][1][wc * 4 + j][lane * 8];
    WAIT_LGKM0();                               // my reads of buf[cur] done
    __builtin_amdgcn_sched_barrier(0);
    SBAR();                                     // everyone's reads done -> reuse ok
    if (kt < 14) STAGE(cur, (kt + 2) * 32);     // prefetch 2 ahead into freed buf
#pragma unroll
    for (int i = 0; i < 4; ++i)
#pragma unroll
      for (int j = 0; j < 4; ++j)
        acc[i][j] = __builtin_amdgcn_mfma_f32_16x16x32_bf16(af[i], bfr[j], acc[i][j], 0, 0, 0);
  }
#undef STAGE

  // Q pre-scaled by head_dim^-0.5 * log2(e) so softmax runs in exp2 domain
  const float sc = 0.17677669529663687f * 1.4426950408889634f;
#pragma unroll
  for (int i = 0; i < 4; ++i) {
    const int mbase = m0 + (wr * 4 + i) * 16 + ((lane >> 4) << 2);
#pragma unroll
    for (int j = 0; j < 4; ++j) {
      const int c = n0 + (wc * 4 + j) * 16 + arow;
      const float bv = bias[c];
#pragma unroll
      for (int r = 0; r < 4; ++r) {
        float val = acc[i][j][r] + bv;
        const int mm = mbase + r;
        const int bb = mm >> 8, tt = mm & 255;
        if (MODE == 0) {
          const int part = c >> 9;
          const int hh = (c >> 5) & 15;
          const int dd = c & 31;
          const size_t off = ((size_t)(bb * 16 + hh) * 256 + tt) * 32 + dd;
          if (part == 0)       qo[off] = f2bf(val * sc);
          else if (part == 1)  ko[off] = f2bf(val);
          else                 vo[off] = f2bf(val);
        } else {
          if (tt < 240) fo[(size_t)(bb * 240 + tt) * 512 + c] = val;
        }
      }
    }
  }
}

// ---------------------------------------------------------------- attention
// One WG (4 waves) per (b,h). Swapped QK^T: lane holds S[q=lane&15][k=j*16+4g+r]
// -> softmax row fully lane-local (2 shfl per reduce); P packs directly into
// the A-fragment of mfma_f32_16x16x16_bf16 for PV (no LDS transpose).
__global__ __launch_bounds__(256, 4)
void k_attn(const short* __restrict__ Qg, const short* __restrict__ Kg,
            const short* __restrict__ Vg, const float* __restrict__ expB,
            short* __restrict__ O) {
  __shared__ alignas(16) short ldsK[15 * 512];      // frag-ordered K tiles
  __shared__ alignas(16) short ldsVT[32 * 260];     // V^T [d][t], stride 260
  const int lane = threadIdx.x & 63;
  const int w = threadIdx.x >> 6;
  const int bh = blockIdx.x;
  const int h = bh & 15, b = bh >> 4;
  const short* Qb = Qg + (size_t)bh * 8192;
  const short* Kb = Kg + (size_t)bh * 8192;
  const short* Vb = Vg + (size_t)bh * 8192;
  const int arow = lane & 15;
  const int g = lane >> 4;

#pragma unroll
  for (int kt = 0; kt < 15; ++kt)
    if ((kt & 3) == w)
      gload_lds16(Kb + (kt * 16 + arow) * 32 + g * 8, &ldsK[kt * 512]);

  // build V^T in LDS (coalesced global reads, conflict-free scalar writes)
#pragma unroll
  for (int p = 0; p < 4; ++p) {
    int gi = p * 256 + threadIdx.x;
    int t = gi >> 2, dg = (gi & 3) * 8;
    bf16x8 v = *(const bf16x8*)(Vb + t * 32 + dg);
#pragma unroll
    for (int e = 0; e < 8; ++e)
      ldsVT[(dg + e) * 260 + t] = v[e];
  }

  bf16x8 qf[4];
#pragma unroll
  for (int i = 0; i < 4; ++i)
    qf[i] = *(const bf16x8*)(Qb + ((w * 4 + i) * 16 + arow) * 32 + g * 8);
  __syncthreads();

  const f32x4 zf = {0.f, 0.f, 0.f, 0.f};
#pragma unroll
  for (int qt = 0; qt < 4; ++qt) {
    // ---- QK^T (swapped operands) ----
    f32x4 sacc[15];
#pragma unroll
    for (int j = 0; j < 15; ++j) {
      bf16x8 kf = *(const bf16x8*)&ldsK[j * 512 + lane * 8];
      sacc[j] = __builtin_amdgcn_mfma_f32_16x16x32_bf16(kf, qf[qt], zf, 0, 0, 0);
    }
    // ---- row max (row is lane-local, then 2-shfl butterfly across groups) ----
    float m = fmaxf(fmaxf(sacc[0][0], sacc[0][1]), fmaxf(sacc[0][2], sacc[0][3]));
#pragma unroll
    for (int j = 1; j < 15; ++j)
      m = fmaxf(m, fmaxf(fmaxf(sacc[j][0], sacc[j][1]), fmaxf(sacc[j][2], sacc[j][3])));
    m = fmaxf(m, __shfl_xor(m, 16));
    m = fmaxf(m, __shfl_xor(m, 32));
    // ---- p = exp2(S - m) * exp(bias), pack to bf16 A-frags ----
    const float* ebp = expB + (size_t)((h * 16 + w * 4 + qt) * 15) * 256 + lane * 4;
    float sum = 0.f;
    s16x4 pa[15];
#pragma unroll
    for (int j = 0; j < 15; ++j) {
      float4 eb = *(const float4*)(ebp + j * 256);
      float p0 = __builtin_amdgcn_exp2f(sacc[j][0] - m) * eb.x;
      float p1 = __builtin_amdgcn_exp2f(sacc[j][1] - m) * eb.y;
      float p2 = __builtin_amdgcn_exp2f(sacc[j][2] - m) * eb.z;
      float p3 = __builtin_amdgcn_exp2f(sacc[j][3] - m) * eb.w;
      sum += (p0 + p1) + (p2 + p3);
      i32x2 pk;
      asm("v_cvt_pk_bf16_f32 %0, %1, %2" : "=v"(pk.x) : "v"(p0), "v"(p1));
      asm("v_cvt_pk_bf16_f32 %0, %1, %2" : "=v"(pk.y) : "v"(p2), "v"(p3));
      pa[j] = __builtin_bit_cast(s16x4, pk);
    }
    sum += __shfl_xor(sum, 16);
    sum += __shfl_xor(sum, 32);
    float rs = __builtin_amdgcn_rcpf(sum);
    // redistribute 1/sum from row-holder lanes (arow=q) to out-row lanes (4g+r)
    float rsr[4];
#pragma unroll
    for (int r = 0; r < 4; ++r)
      rsr[r] = __shfl(rs, (lane & 48) + ((lane & 48) >> 2) + r, 64);
    // ---- PV: P A-frags x V^T B-frags, K=16 ----
    f32x4 oacc[2] = {};
#pragma unroll
    for (int j = 0; j < 15; ++j) {
#pragma unroll
      for (int dt = 0; dt < 2; ++dt) {
        s16x4 vt = *(const s16x4*)&ldsVT[(dt * 16 + arow) * 260 + j * 16 + g * 4];
        oacc[dt] = mfma16(pa[j], vt, oacc[dt]);
      }
    }
    const int q0 = (w * 4 + qt) * 16;
#pragma unroll
    for (int dt = 0; dt < 2; ++dt)
#pragma unroll
      for (int r = 0; r < 4; ++r)
        O[(size_t)(b * 256 + q0 + 4 * g + r) * 512 + h * 32 + dt * 16 + arow] =
            f2bf(oacc[dt][r] * rsr[r]);
  }
}

// ---------------------------------------------------------------- launch

extern "C" void kernel_launch(void* const* d_in, const int* in_sizes, int n_in,
                              void* d_out, int out_size, void* d_ws, size_t ws_size,
                              hipStream_t stream) {
  const float* x      = (const float*)d_in[0];
  const float* qkv_w  = (const float*)d_in[1];
  const float* qkv_b  = (const float*)d_in[2];
  const float* proj_w = (const float*)d_in[3];
  const float* proj_b = (const float*)d_in[4];
  const float* table  = (const float*)d_in[5];
  float* out = (float*)d_out;

  char* ws = (char*)d_ws;
  short* xb      = (short*)(ws);                 // 33,554,432 B (reused as attn_out)
  short* Qg      = (short*)(ws + 33554432u);     // 33,554,432 B
  short* Kg      = (short*)(ws + 67108864u);     // 33,554,432 B
  short* Vg      = (short*)(ws + 100663296u);    // 33,554,432 B
  float* expBf   = (float*)(ws + 134217728u);    //  3,932,160 B
  short* qkv_wt  = (short*)(ws + 138412032u);    //  1,572,864 B
  short* proj_wt = (short*)(ws + 139984896u);    //    524,288 B

  k_convert_x<<<16384, 256, 0, stream>>>(x, xb);
  k_transpose_w<<<(1536 * 512) / 256, 256, 0, stream>>>(qkv_w, qkv_wt, 512, 1536);
  k_transpose_w<<<(512 * 512) / 256, 256, 0, stream>>>(proj_w, proj_wt, 512, 512);
  k_biasfrag<<<960, 256, 0, stream>>>(table, expBf);
  k_gemm<0, 12><<<3072, 256, 0, stream>>>(xb, qkv_wt, qkv_b, Qg, Kg, Vg, nullptr);
  k_attn<<<2048, 256, 0, stream>>>(Qg, Kg, Vg, expBf, xb);
  k_gemm<1, 4><<<1024, 256, 0, stream>>>(xb, proj_wt, proj_b, nullptr, nullptr, nullptr, out);
}